// Round 2
// baseline (6804.884 us; speedup 1.0000x reference)
//
#include <hip/hip_runtime.h>

// Persistent 4-layer LSTM, MFMA split-bf16, fence-free sc0sc1 coherence.
// H=256, B=32, SEQ=1024, L=4.
//
// Grid: 128 WGs x 256 thr. WG (l, w): layer l (bx>>5), owns units [w*8, w*8+8)
// x 4 gates = 32 gate-rows x all 32 batches. GEMM/step: D[m=32 batch][n=32 rows]
// = v[32][512] * Wcat^T, K = 512 (x(256) || h(256)).
// Wave q: mh=q&1 (batch half), nh=q>>1 (row half) -> one 16x16 C-tile.
// Weights resident in VGPRs as bf16 hi/lo (3-term split: hh + hl + lh).
// v comes from global packed-dword buffers ((hi<<16)|lo), loaded with sc0 sc1
// (coherence-point) asm loads -> no fences needed.
//
// Sync design (round 2 — safe recapture of round-1 intent):
//   * flags[l*32+w] = completed-iteration count of WG (l,w), published by tid0
//     via PRIVATE atomicAdd (RMW at coherence point, zero cross-WG contention;
//     baseline's 32-way RMW on one line serialized ~2-3k cy/step).
//   * wave 0 polls ALL dependencies in ONE load round trip: lanes 0..31 check
//     own-layer flags (>= t), lanes 32..63 below-layer flags (>= t+1); __all;
//     then __syncthreads releases the WG (keeps the baseline's proven
//     observation->use visibility margin; round-1's immediate-use raced).
//   * layer-0 x loads pre-issued before the poll (static input); drained by
//     vmcnt(16) after the h-issue (non-polling waves never hit a vmcnt(0)).
//   * out[] store after the flag publish (off the recurrence critical path).

#define HID  256
#define BAT  32
#define SEQL 1024
#define NLAY 4
#define NE   (HID*BAT)       // 8192
#define WGPL 32              // WGs per layer
#define GSTR 36              // lds gate-exchange row stride (floats)

typedef __attribute__((ext_vector_type(8))) short bf16x8;
typedef __attribute__((ext_vector_type(4))) float f32x4;

union U8 { bf16x8 v; unsigned short s[8]; unsigned u[4]; };

__device__ __forceinline__ unsigned short bf16_rne(float f) {
    unsigned u = __float_as_uint(f);
    u += 0x7FFFu + ((u >> 16) & 1u);
    return (unsigned short)(u >> 16);
}
__device__ __forceinline__ float bf16_to_f(unsigned short h) {
    return __uint_as_float(((unsigned)h) << 16);
}
__device__ __forceinline__ unsigned pack_hl(float f) {
    unsigned short hi = bf16_rne(f);
    unsigned short lo = bf16_rne(f - bf16_to_f(hi));
    return (((unsigned)hi) << 16) | lo;
}

__device__ __forceinline__ uint4 ld_cohx4(const unsigned* p) {
    uint4 r;
    asm volatile("global_load_dwordx4 %0, %1, off sc0 sc1" : "=v"(r) : "v"(p) : "memory");
    return r;
}
__device__ __forceinline__ void st_coh(unsigned* p, unsigned v) {
    asm volatile("global_store_dword %0, %1, off sc0 sc1" :: "v"(p), "v"(v) : "memory");
}
__device__ __forceinline__ void waitcnt0() {
    asm volatile("s_waitcnt vmcnt(0)" ::: "memory");
}

__device__ __forceinline__ float sigm(float x)  { return 1.0f / (1.0f + __expf(-x)); }
__device__ __forceinline__ float tanhx(float x) { return 1.0f - 2.0f / (__expf(2.0f * x) + 1.0f); }

// In-place pack of layer-0 input x: fp32 -> (bf16hi<<16)|bf16lo, elementwise.
__global__ __launch_bounds__(256) void pack_x(unsigned* xp) {
    int i = (blockIdx.x * 256 + threadIdx.x) * 4;   // SEQ*NE = 8192*1024 covered exactly
    float4 f = *(const float4*)((const float*)xp + i);
    uint4 u;
    u.x = pack_hl(f.x); u.y = pack_hl(f.y);
    u.z = pack_hl(f.z); u.w = pack_hl(f.w);
    *(uint4*)(xp + i) = u;
}

__global__ __launch_bounds__(256, 1)
void lstm_mfma(unsigned* __restrict__ hslab,       // h_data as dwords (slots s>=1 = hbuf)
               const float* __restrict__ c_data,
               const float* __restrict__ W,
               const float* __restrict__ R,
               const float* __restrict__ bias,
               const unsigned* __restrict__ xpack,  // x_data slab 0, packed
               float* __restrict__ out,
               int* __restrict__ flags)
{
    __shared__ float ldsg[32 * GSTR];

    const int tid  = threadIdx.x;
    const int bx   = blockIdx.x;
    const int l    = bx >> 5;
    const int w    = bx & 31;

    const int wv   = tid >> 6;
    const int lane = tid & 63;
    const int mh   = wv & 1;          // batch half
    const int nh   = wv >> 1;         // row half
    const int ln15 = lane & 15;
    const int kq   = lane >> 4;       // 0..3 k-block

    const int n_loc = nh * 16 + ln15;             // local gate-row 0..31
    const int gate  = n_loc >> 3;
    const int uu    = n_loc & 7;
    const int grow  = gate * HID + w * 8 + uu;    // global gate-row in [0,1024)
    const int bg    = mh * 16 + ln15;             // batch for A-frags

    // ---- poll setup (used by wave 0 only): lanes 0..31 own-layer flags,
    //      lanes 32..63 below-layer flags ----
    const int pl = lane & 31;
    const int* fpoll = (lane < 32) ? (flags + l * 32 + pl)
                     : ((l > 0)    ? (flags + (l - 1) * 32 + pl)
                                   : (flags + pl));
    // threshold at iteration t is thr_base + t:
    //   own-layer: need >= t   (all peers finished iter t-1)
    //   below:     need >= t+1 (below finished iter t -> wrote slot t+1)
    //   l==0 lanes 32..63: always pass
    const int thr_base = (lane < 32) ? 0 : ((l > 0) ? 1 : -0x40000000);

    // ---- resident weight fragments: Bhi/Blo[s], s=0..15 (K=512) ----
    bf16x8 Bhi[16], Blo[16];
    {
        const float* Wl = W + (size_t)l * 4 * HID * HID;
        const float* Rl = R + (size_t)l * 4 * HID * HID;
        #pragma unroll
        for (int s = 0; s < 16; ++s) {
            int k0 = s * 32 + kq * 8;
            const float* src = (k0 < HID) ? (Wl + (size_t)grow * HID + k0)
                                          : (Rl + (size_t)grow * HID + (k0 - HID));
            float4 f0 = *(const float4*)src;
            float4 f1 = *(const float4*)(src + 4);
            float ff[8] = {f0.x, f0.y, f0.z, f0.w, f1.x, f1.y, f1.z, f1.w};
            U8 hi, lo;
            #pragma unroll
            for (int j = 0; j < 8; ++j) {
                hi.s[j] = bf16_rne(ff[j]);
                lo.s[j] = bf16_rne(ff[j] - bf16_to_f(hi.s[j]));
            }
            Bhi[s] = hi.v; Blo[s] = lo.v;
        }
    }

    const float bias_n = bias[l * 4 * HID + grow];

    // c-state owner: thread (uu2, b2)
    const int uu2 = tid >> 5;
    const int b2  = tid & 31;
    float cst = c_data[(size_t)l * (SEQL + 1) * NE + b2 * HID + w * 8 + uu2];

    unsigned* hbuf = hslab;  // slot (l,s) at ((l*(SEQL+1))+s)*NE
    const float* h0f = (const float*)hslab + (size_t)l * (SEQL + 1) * NE;

    for (int t = 0; t < SEQL; ++t) {
        const unsigned* xsrc = (l == 0)
            ? (xpack + (size_t)t * NE)
            : (hbuf + ((size_t)(l - 1) * (SEQL + 1) + (t + 1)) * NE);

        uint4 araw[32];

        // ---- layer 0, t>0: x is static input -> issue loads BEFORE the poll
        //      (latency hides under the flag wait) ----
        if (l == 0 && t > 0) {
            #pragma unroll
            for (int s = 0; s < 8; ++s) {
                const unsigned* p = xsrc + bg * HID + s * 32 + kq * 8;
                araw[2 * s]     = ld_cohx4(p);
                araw[2 * s + 1] = ld_cohx4(p + 4);
            }
        }

        // ---- dependency wait: wave 0 polls (1 load round trip covers BOTH
        //      dependency sets), then __syncthreads releases the WG ----
        if (wv == 0) {
            const int thr = thr_base + t;
            for (;;) {
                int v = __hip_atomic_load(fpoll, __ATOMIC_RELAXED,
                                          __HIP_MEMORY_SCOPE_AGENT);
                if (__all(v >= thr)) break;
                __builtin_amdgcn_s_sleep(1);
            }
        }
        __syncthreads();

        // ---- issue remaining A-fragment loads ----
        if (t > 0) {
            const unsigned* hsrc = hbuf + ((size_t)l * (SEQL + 1) + t) * NE;
            if (l > 0) {
                #pragma unroll
                for (int s = 0; s < 8; ++s) {
                    const unsigned* p = xsrc + bg * HID + s * 32 + kq * 8;
                    araw[2 * s]     = ld_cohx4(p);
                    araw[2 * s + 1] = ld_cohx4(p + 4);
                }
            }
            #pragma unroll
            for (int s = 8; s < 16; ++s) {
                const unsigned* p = hsrc + bg * HID + (s - 8) * 32 + kq * 8;
                araw[2 * s]     = ld_cohx4(p);
                araw[2 * s + 1] = ld_cohx4(p + 4);
            }
            // x-part = oldest 16 outstanding for every wave (polling wave 0
            // drained its flag loads inside the poll; x loads were issued
            // before any flag load it is still waiting on at exit).
            asm volatile("s_waitcnt vmcnt(16)" ::: "memory");
        } else {
            #pragma unroll
            for (int s = 0; s < 8; ++s) {
                const unsigned* p = xsrc + bg * HID + s * 32 + kq * 8;
                araw[2 * s]     = ld_cohx4(p);
                araw[2 * s + 1] = ld_cohx4(p + 4);
            }
            #pragma unroll
            for (int s = 8; s < 16; ++s) {   // h0 is fp32 in h_data slot 0
                const float* hp = h0f + bg * HID + (s - 8) * 32 + kq * 8;
                float4 f0 = *(const float4*)hp;
                float4 f1 = *(const float4*)(hp + 4);
                uint4 a0, a1;
                a0.x = pack_hl(f0.x); a0.y = pack_hl(f0.y);
                a0.z = pack_hl(f0.z); a0.w = pack_hl(f0.w);
                a1.x = pack_hl(f1.x); a1.y = pack_hl(f1.y);
                a1.z = pack_hl(f1.z); a1.w = pack_hl(f1.w);
                araw[2 * s] = a0; araw[2 * s + 1] = a1;
            }
            waitcnt0();
        }

        // ---- MFMA K-loop: 3-term split-bf16, 3 independent acc chains ----
        f32x4 acc0 = {bias_n, bias_n, bias_n, bias_n};
        f32x4 acc1 = {0.f, 0.f, 0.f, 0.f};
        f32x4 acc2 = {0.f, 0.f, 0.f, 0.f};
        #pragma unroll
        for (int s = 0; s < 16; ++s) {
            if (s == 8 && t > 0) waitcnt0();   // h-part ready
            uint4 d0 = araw[2 * s], d1 = araw[2 * s + 1];
            U8 ahi, alo;
            ahi.u[0] = __builtin_amdgcn_perm(d0.y, d0.x, 0x07060302u);
            ahi.u[1] = __builtin_amdgcn_perm(d0.w, d0.z, 0x07060302u);
            ahi.u[2] = __builtin_amdgcn_perm(d1.y, d1.x, 0x07060302u);
            ahi.u[3] = __builtin_amdgcn_perm(d1.w, d1.z, 0x07060302u);
            alo.u[0] = __builtin_amdgcn_perm(d0.y, d0.x, 0x05040100u);
            alo.u[1] = __builtin_amdgcn_perm(d0.w, d0.z, 0x05040100u);
            alo.u[2] = __builtin_amdgcn_perm(d1.y, d1.x, 0x05040100u);
            alo.u[3] = __builtin_amdgcn_perm(d1.w, d1.z, 0x05040100u);
            acc0 = __builtin_amdgcn_mfma_f32_16x16x32_bf16(ahi.v, Bhi[s], acc0, 0, 0, 0);
            acc1 = __builtin_amdgcn_mfma_f32_16x16x32_bf16(ahi.v, Blo[s], acc1, 0, 0, 0);
            acc2 = __builtin_amdgcn_mfma_f32_16x16x32_bf16(alo.v, Bhi[s], acc2, 0, 0, 0);
        }
        f32x4 cc = acc0 + acc1;
        cc = cc + acc2;

        // ---- exchange gates via LDS: ldsg[n][m], D: m=(lane>>4)*4+r, n=lane&15 ----
        *(f32x4*)&ldsg[n_loc * GSTR + mh * 16 + kq * 4] = cc;
        __syncthreads();

        // ---- elementwise update by cell owner (uu2, b2) ----
        float hv;
        {
            float gi = ldsg[(0 * 8 + uu2) * GSTR + b2];
            float gf = ldsg[(1 * 8 + uu2) * GSTR + b2];
            float gg = ldsg[(2 * 8 + uu2) * GSTR + b2];
            float go = ldsg[(3 * 8 + uu2) * GSTR + b2];
            float iv = sigm(gi), fv = sigm(gf), gv = tanhx(gg), ov = sigm(go);
            cst = fv * cst + iv * gv;
            hv = ov * tanhx(cst);
            unsigned dw = pack_hl(hv);
            unsigned* dst = hbuf + ((size_t)l * (SEQL + 1) + (t + 1)) * NE
                          + b2 * HID + w * 8 + uu2;
            st_coh(dst, dw);
        }
        waitcnt0();          // every wave drains its own h stores
        __syncthreads();     // all 256 threads drained -> epoch can be published

        if (tid == 0)
            __hip_atomic_fetch_add(&flags[l * 32 + w], 1,
                                   __ATOMIC_RELAXED, __HIP_MEMORY_SCOPE_AGENT);

        // out store AFTER the flag publish: off the recurrence critical path
        if (l == NLAY - 1)
            out[(size_t)t * NE + b2 * HID + w * 8 + uu2] = hv;
    }
}

extern "C" void kernel_launch(void* const* d_in, const int* in_sizes, int n_in,
                              void* d_out, int out_size, void* d_ws, size_t ws_size,
                              hipStream_t stream) {
    unsigned*    h_data = (unsigned*)d_in[0];
    unsigned*    x_data = (unsigned*)d_in[1];
    float*       c_data = (float*)d_in[2];
    const float* W      = (const float*)d_in[3];
    const float* R      = (const float*)d_in[4];
    const float* bias   = (const float*)d_in[5];
    float* out = (float*)d_out;

    const size_t flag_bytes = (size_t)NLAY * WGPL * sizeof(int);
    int* flags;
    if (ws_size >= flag_bytes) flags = (int*)d_ws;
    else                       flags = (int*)(c_data + NE);  // c_data slot [0][1]: unused
    hipMemsetAsync(flags, 0, flag_bytes, stream);

    // pack layer-0 x in place (SEQ*NE elements = 8192 blocks * 256 thr * 4)
    pack_x<<<dim3(8192), dim3(256), 0, stream>>>(x_data);

    lstm_mfma<<<dim3(NLAY * WGPL), dim3(256), 0, stream>>>(
        h_data, c_data, W, R, bias, x_data, out, flags);
}